// Round 4
// baseline (672.220 us; speedup 1.0000x reference)
//
#include <hip/hip_runtime.h>
#include <hip/hip_bf16.h>

typedef __bf16 bf16x8 __attribute__((ext_vector_type(8)));
typedef float  f32x4  __attribute__((ext_vector_type(4)));
typedef float  f32x16 __attribute__((ext_vector_type(16)));

static constexpr int S  = 64;    // DIM_S
static constexpr int C  = 8;     // DIM_C (experts)
static constexpr int HD = 256;   // hidden width

__device__ __forceinline__ unsigned short f2bf(float f) {
  __hip_bfloat16 b = __float2bfloat16(f);
  unsigned short u;
  __builtin_memcpy(&u, &b, 2);
  return u;
}

// async global->LDS DMA, 16 B per lane; lds dest = wave-uniform base + lane*16
__device__ __forceinline__ void gl2lds16(const void* g, void* l) {
  __builtin_amdgcn_global_load_lds(
      (const __attribute__((address_space(1))) unsigned int*)g,
      (__attribute__((address_space(3))) unsigned int*)l, 16, 0, 0);
}

// Pack W1/W2 into MFMA-fragment order for mfma_f32_32x32x16_bf16.
// Fragment layout (A and B operands): lane l holds 8 contiguous k at
// k = 8*(l>>5)+e, with m|n = l&31.  (HW-validated: rounds 2-3 refcheck'd.)
__global__ __launch_bounds__(256) void prep_frags(
    const float* __restrict__ W1, const float* __restrict__ W2,
    unsigned short* __restrict__ W1F, unsigned short* __restrict__ W2F)
{
  const int g = blockIdx.x * 256 + threadIdx.x;
  if (blockIdx.x < 256) {          // W2F: 8 experts x 128 frag-groups x 64 lanes
    const int c  = g >> 13, rem = g & 8191;
    const int fg = rem >> 6, l = rem & 63;
    const int ct = fg >> 4, stp = fg & 15;
    const int k0 = stp * 16 + (l >> 5) * 8;
    const int n  = ct * 32 + (l & 31);
    const float* src = W2 + ((size_t)c * 256 + k0) * 256 + n;
    unsigned short* dst = W2F + (size_t)c * 65536 + (size_t)(fg * 64 + l) * 8;
    #pragma unroll
    for (int e = 0; e < 8; ++e) dst[e] = f2bf(src[(size_t)e * 256]);
  } else {                         // W1F: 8 experts x 32 frag-groups x 64 lanes
    const int gg = g - 65536;
    const int c  = gg >> 11, rem = gg & 2047;
    const int fg = rem >> 6, l = rem & 63;
    const int mt = fg >> 2, ks = fg & 3;
    const int s0 = ks * 16 + (l >> 5) * 8;
    const int h  = mt * 32 + (l & 31);
    const float* src = W1 + ((size_t)c * 64 + s0) * 256 + h;
    unsigned short* dst = W1F + (size_t)c * 16384 + (size_t)(fg * 64 + l) * 8;
    #pragma unroll
    for (int e = 0; e < 8; ++e) dst[e] = f2bf(src[(size_t)e * 256]);
  }
}

// 256 blocks (1/CU) x 512 threads (8 waves x 64 batch rows), one expert/block.
// W2F (128KB) DMA'd to LDS once; 4 jobs of 512 rows; ONE barrier total.
// This round: explicit software pipelines (phase-2 half-ct LDS ping-pong,
// phase-1 W1 double-buffer, T14 early st loads for job+1), bias folded into
// MFMA C-in, cvt_pk packing, setprio around MFMA clusters.
__global__ __launch_bounds__(512, 2) void moe_fused(
    const float* __restrict__ st,
    const unsigned short* __restrict__ W1F,
    const unsigned short* __restrict__ W2F,
    const float* __restrict__ b1,
    const float* __restrict__ b2,
    const float* __restrict__ W3,
    const float* __restrict__ b3,
    float* __restrict__ out)
{
  __shared__ __align__(16) unsigned short sW2[HD * HD];   // 131072 B

  const int tid  = threadIdx.x;
  const int lane = tid & 63;
  const int wv   = tid >> 6;          // 0..7
  const int l31  = lane & 31;
  const int h5   = lane >> 5;

  const int b    = blockIdx.x;
  const int x    = b & 7;             // XCD (perf heuristic only)
  const int m    = b >> 3;
  const int c    = m & 7;             // expert
  const int sgrp = m >> 3;            // batch stream 0..3

  const unsigned short* W1c = W1F + (size_t)c * 16384;
  const unsigned short* W2c = W2F + (size_t)c * 65536;

  // ---- st prefetch for job 0 (issued FIRST: oldest in vmcnt FIFO) ----
  float4 sraw[16];
  {
    const int wr0 = (x * 16 + sgrp * 4) * 512 + wv * 64;
    #pragma unroll
    for (int nt = 0; nt < 2; ++nt)
      #pragma unroll
      for (int ks = 0; ks < 4; ++ks) {
        const float* rp = st + (size_t)(wr0 + nt * 32 + l31) * S + ks * 16 + h5 * 8;
        sraw[(nt * 4 + ks) * 2]     = *reinterpret_cast<const float4*>(rp);
        sraw[(nt * 4 + ks) * 2 + 1] = *reinterpret_cast<const float4*>(rp + 4);
      }
  }

  // ---- one-time DMA: whole W2F[c] -> LDS (linear, 1KB per wave-slot) ----
  #pragma unroll
  for (int it = 0; it < 16; ++it) {
    const int slot = it * 8 + wv;          // 128 slots x 1024 B
    gl2lds16(W2c + slot * 512 + lane * 8, sW2 + slot * 512);
  }

  // ---- per-block scalars ----
  float b2v[8], w3v[8];
  #pragma unroll
  for (int ct = 0; ct < 8; ++ct) {
    b2v[ct] = b2[c * HD + ct * 32 + l31];
    w3v[ct] = W3[c * HD + ct * 32 + l31];
  }
  const float bb3 = b3[c];

  for (int ji = 0; ji < 4; ++ji) {
    const int tile = x * 16 + sgrp * 4 + ji;
    const int wrow = tile * 512 + wv * 64;

    // ---- convert prefetched st rows -> phase-1 B frags (cvt_pk) ----
    bf16x8 bB[4][2];   // [ks][nt]
    #pragma unroll
    for (int nt = 0; nt < 2; ++nt)
      #pragma unroll
      for (int ks = 0; ks < 4; ++ks) {
        float4 xx = sraw[(nt * 4 + ks) * 2];
        float4 yy = sraw[(nt * 4 + ks) * 2 + 1];
        union { bf16x8 v; unsigned u[4]; } pk;
        __asm__("v_cvt_pk_bf16_f32 %0, %1, %2" : "=v"(pk.u[0]) : "v"(xx.x), "v"(xx.y));
        __asm__("v_cvt_pk_bf16_f32 %0, %1, %2" : "=v"(pk.u[1]) : "v"(xx.z), "v"(xx.w));
        __asm__("v_cvt_pk_bf16_f32 %0, %1, %2" : "=v"(pk.u[2]) : "v"(yy.x), "v"(yy.y));
        __asm__("v_cvt_pk_bf16_f32 %0, %1, %2" : "=v"(pk.u[3]) : "v"(yy.z), "v"(yy.w));
        bB[ks][nt] = pk.v;
      }

    // ---- phase 1: h1^T = W1^T @ st^T, W1-frag double-buffered ----
    bf16x8 aF[2][16];   // phase-2 A-frags
    bf16x8 aWc[4], aWn[4];
    #pragma unroll
    for (int ks = 0; ks < 4; ++ks)
      aWc[ks] = *reinterpret_cast<const bf16x8*>(W1c + (size_t)(ks * 64 + lane) * 8);

    #pragma unroll
    for (int mt = 0; mt < 8; ++mt) {
      if (mt < 7) {
        #pragma unroll
        for (int ks = 0; ks < 4; ++ks)
          aWn[ks] = *reinterpret_cast<const bf16x8*>(
              W1c + (size_t)(((mt + 1) * 4 + ks) * 64 + lane) * 8);
      }
      // b1 bias folded into MFMA C-in (reg layout matches D rows 8g+4h5+j)
      union { f32x4 q[4]; f32x16 v; } bu;
      #pragma unroll
      for (int gq = 0; gq < 4; ++gq)
        bu.q[gq] = *reinterpret_cast<const f32x4*>(
            b1 + c * HD + mt * 32 + 8 * gq + 4 * h5);

      __builtin_amdgcn_s_setprio(1);
      f32x16 acc0 = __builtin_amdgcn_mfma_f32_32x32x16_bf16(aWc[0], bB[0][0], bu.v, 0, 0, 0);
      f32x16 acc1 = __builtin_amdgcn_mfma_f32_32x32x16_bf16(aWc[0], bB[0][1], bu.v, 0, 0, 0);
      #pragma unroll
      for (int ks = 1; ks < 4; ++ks) {
        acc0 = __builtin_amdgcn_mfma_f32_32x32x16_bf16(aWc[ks], bB[ks][0], acc0, 0, 0, 0);
        acc1 = __builtin_amdgcn_mfma_f32_32x32x16_bf16(aWc[ks], bB[ks][1], acc1, 0, 0, 0);
      }
      __builtin_amdgcn_s_setprio(0);

      // relu -> bf16 -> in-register transpose (cvt_pk + permlane32_swap)
      #pragma unroll
      for (int rt = 0; rt < 2; ++rt) {
        const f32x16& A = rt ? acc1 : acc0;
        unsigned d[8];
        #pragma unroll
        for (int p = 0; p < 8; ++p) {
          float v0 = A[2 * p];     v0 = v0 > 0.f ? v0 : 0.f;
          float v1 = A[2 * p + 1]; v1 = v1 > 0.f ? v1 : 0.f;
          __asm__("v_cvt_pk_bf16_f32 %0, %1, %2" : "=v"(d[p]) : "v"(v0), "v"(v1));
        }
        __asm__("v_permlane32_swap_b32 %0, %1" : "+v"(d[0]), "+v"(d[2]));
        __asm__("v_permlane32_swap_b32 %0, %1" : "+v"(d[1]), "+v"(d[3]));
        __asm__("v_permlane32_swap_b32 %0, %1" : "+v"(d[4]), "+v"(d[6]));
        __asm__("v_permlane32_swap_b32 %0, %1" : "+v"(d[5]), "+v"(d[7]));
        union { unsigned u[4]; bf16x8 v; } f0, f1;
        f0.u[0] = d[0]; f0.u[1] = d[1]; f0.u[2] = d[2]; f0.u[3] = d[3];
        f1.u[0] = d[4]; f1.u[1] = d[5]; f1.u[2] = d[6]; f1.u[3] = d[7];
        aF[rt][2 * mt]     = f0.v;
        aF[rt][2 * mt + 1] = f1.v;
      }
      if (mt < 7) {
        #pragma unroll
        for (int ks = 0; ks < 4; ++ks) aWc[ks] = aWn[ks];
      }
    }

    if (ji == 0) __syncthreads();   // W2 DMA landed (vmcnt drain + all waves)

    // ---- phase 2+3: half-ct LDS ping-pong, b2 folded into C-in ----
    bf16x8 fA[8], fB[8];
    #pragma unroll
    for (int s = 0; s < 8; ++s)
      fA[s] = *reinterpret_cast<const bf16x8*>(sW2 + (size_t)(s * 64 + lane) * 8);

    float dacc0[16], dacc1[16];
    #pragma unroll
    for (int r = 0; r < 16; ++r) { dacc0[r] = 0.f; dacc1[r] = 0.f; }

    #pragma unroll
    for (int ct = 0; ct < 8; ++ct) {
      #pragma unroll
      for (int s = 0; s < 8; ++s)
        fB[s] = *reinterpret_cast<const bf16x8*>(
            sW2 + (size_t)((ct * 16 + 8 + s) * 64 + lane) * 8);

      f32x16 b2i;
      #pragma unroll
      for (int r = 0; r < 16; ++r) b2i[r] = b2v[ct];

      __builtin_amdgcn_s_setprio(1);
      f32x16 acc0 = __builtin_amdgcn_mfma_f32_32x32x16_bf16(aF[0][0], fA[0], b2i, 0, 0, 0);
      f32x16 acc1 = __builtin_amdgcn_mfma_f32_32x32x16_bf16(aF[1][0], fA[0], b2i, 0, 0, 0);
      #pragma unroll
      for (int s = 1; s < 8; ++s) {
        acc0 = __builtin_amdgcn_mfma_f32_32x32x16_bf16(aF[0][s], fA[s], acc0, 0, 0, 0);
        acc1 = __builtin_amdgcn_mfma_f32_32x32x16_bf16(aF[1][s], fA[s], acc1, 0, 0, 0);
      }
      __builtin_amdgcn_s_setprio(0);

      if (ct < 7) {
        #pragma unroll
        for (int s = 0; s < 8; ++s)
          fA[s] = *reinterpret_cast<const bf16x8*>(
              sW2 + (size_t)(((ct + 1) * 16 + s) * 64 + lane) * 8);
      }

      __builtin_amdgcn_s_setprio(1);
      #pragma unroll
      for (int s = 0; s < 8; ++s) {
        acc0 = __builtin_amdgcn_mfma_f32_32x32x16_bf16(aF[0][8 + s], fB[s], acc0, 0, 0, 0);
        acc1 = __builtin_amdgcn_mfma_f32_32x32x16_bf16(aF[1][8 + s], fB[s], acc1, 0, 0, 0);
      }
      __builtin_amdgcn_s_setprio(0);

      #pragma unroll
      for (int r = 0; r < 16; ++r) {
        float v0 = acc0[r]; v0 = v0 > 0.f ? v0 : 0.f; dacc0[r] += v0 * w3v[ct];
        float v1 = acc1[r]; v1 = v1 > 0.f ? v1 : 0.f; dacc1[r] += v1 * w3v[ct];
      }
    }

    // ---- T14: issue next job's st loads under the reduce+store ----
    if (ji < 3) {
      const int wrn = (tile + 1) * 512 + wv * 64;
      #pragma unroll
      for (int nt = 0; nt < 2; ++nt)
        #pragma unroll
        for (int ks = 0; ks < 4; ++ks) {
          const float* rp = st + (size_t)(wrn + nt * 32 + l31) * S + ks * 16 + h5 * 8;
          sraw[(nt * 4 + ks) * 2]     = *reinterpret_cast<const float4*>(rp);
          sraw[(nt * 4 + ks) * 2 + 1] = *reinterpret_cast<const float4*>(rp + 4);
        }
    }

    // ---- reduce over 32 n-lanes, write out ----
    #pragma unroll
    for (int r = 0; r < 16; ++r) {
      float v0 = dacc0[r], v1 = dacc1[r];
      v0 += __shfl_xor(v0, 1);  v1 += __shfl_xor(v1, 1);
      v0 += __shfl_xor(v0, 2);  v1 += __shfl_xor(v1, 2);
      v0 += __shfl_xor(v0, 4);  v1 += __shfl_xor(v1, 4);
      v0 += __shfl_xor(v0, 8);  v1 += __shfl_xor(v1, 8);
      v0 += __shfl_xor(v0, 16); v1 += __shfl_xor(v1, 16);
      dacc0[r] = v0; dacc1[r] = v1;
    }

    if (l31 == 0) {   // lanes 0 and 32 write (h5 splits the row groups)
      #pragma unroll
      for (int r = 0; r < 16; ++r) {
        const int rr = (r & 3) + 8 * (r >> 2) + 4 * h5;   // D row in 32-tile
        out[(size_t)(wrow + rr) * C + c]      = dacc0[r] + bb3;
        out[(size_t)(wrow + 32 + rr) * C + c] = dacc1[r] + bb3;
      }
    }
  }
}

extern "C" void kernel_launch(void* const* d_in, const int* in_sizes, int n_in,
                              void* d_out, int out_size, void* d_ws, size_t ws_size,
                              hipStream_t stream)
{
  const float* st = (const float*)d_in[0];
  const float* W1 = (const float*)d_in[1];
  const float* b1 = (const float*)d_in[2];
  const float* W2 = (const float*)d_in[3];
  const float* b2 = (const float*)d_in[4];
  const float* W3 = (const float*)d_in[5];
  const float* b3 = (const float*)d_in[6];
  float* out = (float*)d_out;

  unsigned short* W1F = (unsigned short*)d_ws;         // 131072 bf16
  unsigned short* W2F = W1F + C * HD * S;              // 524288 bf16

  prep_frags<<<dim3(320), dim3(256), 0, stream>>>(W1, W2, W1F, W2F);
  moe_fused<<<dim3(256), dim3(512), 0, stream>>>(st, W1F, W2F, b1, b2, W3, b3, out);
}

// Round 5
// 206.852 us; speedup vs baseline: 3.2498x; 3.2498x over previous
//
#include <hip/hip_runtime.h>
#include <hip/hip_bf16.h>

typedef __bf16 bf16x8 __attribute__((ext_vector_type(8)));
typedef float  f32x4  __attribute__((ext_vector_type(4)));
typedef float  f32x16 __attribute__((ext_vector_type(16)));

static constexpr int S  = 64;    // DIM_S
static constexpr int C  = 8;     // DIM_C (experts)
static constexpr int HD = 256;   // hidden width

__device__ __forceinline__ unsigned short f2bf(float f) {
  __hip_bfloat16 b = __float2bfloat16(f);
  unsigned short u;
  __builtin_memcpy(&u, &b, 2);
  return u;
}

// async global->LDS DMA, 16 B per lane; lds dest = wave-uniform base + lane*16
__device__ __forceinline__ void gl2lds16(const void* g, void* l) {
  __builtin_amdgcn_global_load_lds(
      (const __attribute__((address_space(1))) unsigned int*)g,
      (__attribute__((address_space(3))) unsigned int*)l, 16, 0, 0);
}

// Pack W1/W2 into MFMA-fragment order for mfma_f32_32x32x16_bf16.
// Fragment layout (A and B operands): lane l holds 8 contiguous k at
// k = 8*(l>>5)+e, with m|n = l&31.  (HW-validated: rounds 2-4 refcheck'd.)
__global__ __launch_bounds__(256) void prep_frags(
    const float* __restrict__ W1, const float* __restrict__ W2,
    unsigned short* __restrict__ W1F, unsigned short* __restrict__ W2F)
{
  const int g = blockIdx.x * 256 + threadIdx.x;
  if (blockIdx.x < 256) {          // W2F: 8 experts x 128 frag-groups x 64 lanes
    const int c  = g >> 13, rem = g & 8191;
    const int fg = rem >> 6, l = rem & 63;
    const int ct = fg >> 4, stp = fg & 15;
    const int k0 = stp * 16 + (l >> 5) * 8;
    const int n  = ct * 32 + (l & 31);
    const float* src = W2 + ((size_t)c * 256 + k0) * 256 + n;
    unsigned short* dst = W2F + (size_t)c * 65536 + (size_t)(fg * 64 + l) * 8;
    #pragma unroll
    for (int e = 0; e < 8; ++e) dst[e] = f2bf(src[(size_t)e * 256]);
  } else {                         // W1F: 8 experts x 32 frag-groups x 64 lanes
    const int gg = g - 65536;
    const int c  = gg >> 11, rem = gg & 2047;
    const int fg = rem >> 6, l = rem & 63;
    const int mt = fg >> 2, ks = fg & 3;
    const int s0 = ks * 16 + (l >> 5) * 8;
    const int h  = mt * 32 + (l & 31);
    const float* src = W1 + ((size_t)c * 64 + s0) * 256 + h;
    unsigned short* dst = W1F + (size_t)c * 16384 + (size_t)(fg * 64 + l) * 8;
    #pragma unroll
    for (int e = 0; e < 8; ++e) dst[e] = f2bf(src[(size_t)e * 256]);
  }
}

// 256 blocks (1/CU) x 512 threads (8 waves x 64 batch rows), one expert/block.
// W2F (128KB) DMA'd to LDS once; 4 jobs of 512 rows; ONE barrier total.
// Register budget is the binding constraint: 256 unified regs/wave at
// 8 waves/CU (R4 post-mortem: exceeding it spills to scratch, +1.8GB HBM).
// This round: rolling 4-deep phase-2 B-frag pipeline (16 regs, statically
// indexed), b1/b2 folded into MFMA C-in, no other prefetch state.
__global__ __launch_bounds__(512, 2) void moe_fused(
    const float* __restrict__ st,
    const unsigned short* __restrict__ W1F,
    const unsigned short* __restrict__ W2F,
    const float* __restrict__ b1,
    const float* __restrict__ b2,
    const float* __restrict__ W3,
    const float* __restrict__ b3,
    float* __restrict__ out)
{
  __shared__ __align__(16) unsigned short sW2[HD * HD];   // 131072 B

  const int tid  = threadIdx.x;
  const int lane = tid & 63;
  const int wv   = tid >> 6;          // 0..7
  const int l31  = lane & 31;
  const int h5   = lane >> 5;

  const int b    = blockIdx.x;
  const int x    = b & 7;             // XCD (perf heuristic only)
  const int m    = b >> 3;
  const int c    = m & 7;             // expert
  const int sgrp = m >> 3;            // batch stream 0..3

  const unsigned short* W1c = W1F + (size_t)c * 16384;
  const unsigned short* W2c = W2F + (size_t)c * 65536;

  // ---- one-time DMA: whole W2F[c] -> LDS (issued first; latency hides
  // under all of job-0 phase 1; drained by the single barrier) ----
  #pragma unroll
  for (int it = 0; it < 16; ++it) {
    const int slot = it * 8 + wv;          // 128 slots x 1024 B
    gl2lds16(W2c + slot * 512 + lane * 8, sW2 + slot * 512);
  }

  // ---- per-block scalars ----
  float b2v[8], w3v[8];
  #pragma unroll
  for (int ct = 0; ct < 8; ++ct) {
    b2v[ct] = b2[c * HD + ct * 32 + l31];
    w3v[ct] = W3[c * HD + ct * 32 + l31];
  }
  const float bb3 = b3[c];

  for (int ji = 0; ji < 4; ++ji) {
    const int tile = x * 16 + sgrp * 4 + ji;
    const int wrow = tile * 512 + wv * 64;

    // ---- phase-1 B frags: wave's 64 st rows (fp32 -> bf16 via cvt_pk) ----
    bf16x8 bB[4][2];   // [ks][nt]
    #pragma unroll
    for (int nt = 0; nt < 2; ++nt)
      #pragma unroll
      for (int ks = 0; ks < 4; ++ks) {
        const float* rp = st + (size_t)(wrow + nt * 32 + l31) * S + ks * 16 + h5 * 8;
        float4 xx = *reinterpret_cast<const float4*>(rp);
        float4 yy = *reinterpret_cast<const float4*>(rp + 4);
        union { bf16x8 v; unsigned u[4]; } pk;
        __asm__("v_cvt_pk_bf16_f32 %0, %1, %2" : "=v"(pk.u[0]) : "v"(xx.x), "v"(xx.y));
        __asm__("v_cvt_pk_bf16_f32 %0, %1, %2" : "=v"(pk.u[1]) : "v"(xx.z), "v"(xx.w));
        __asm__("v_cvt_pk_bf16_f32 %0, %1, %2" : "=v"(pk.u[2]) : "v"(yy.x), "v"(yy.y));
        __asm__("v_cvt_pk_bf16_f32 %0, %1, %2" : "=v"(pk.u[3]) : "v"(yy.z), "v"(yy.w));
        bB[ks][nt] = pk.v;
      }

    // ---- phase 1: h1^T = W1^T @ st^T; b1 folded into C-in; relu ->
    // in-register transpose (cvt_pk + permlane32_swap) -> aF ----
    bf16x8 aF[2][16];   // phase-2 A-frags (128 regs, the design invariant)
    #pragma unroll
    for (int mt = 0; mt < 8; ++mt) {
      bf16x8 aW[4];
      #pragma unroll
      for (int ks = 0; ks < 4; ++ks)
        aW[ks] = *reinterpret_cast<const bf16x8*>(
            W1c + (size_t)((mt * 4 + ks) * 64 + lane) * 8);

      union { f32x4 q[4]; f32x16 v; } bu;   // b1 C-in (D rows 8g+4h5+j)
      #pragma unroll
      for (int gq = 0; gq < 4; ++gq)
        bu.q[gq] = *reinterpret_cast<const f32x4*>(
            b1 + c * HD + mt * 32 + 8 * gq + 4 * h5);

      __builtin_amdgcn_s_setprio(1);
      f32x16 acc0 = __builtin_amdgcn_mfma_f32_32x32x16_bf16(aW[0], bB[0][0], bu.v, 0, 0, 0);
      f32x16 acc1 = __builtin_amdgcn_mfma_f32_32x32x16_bf16(aW[0], bB[0][1], bu.v, 0, 0, 0);
      #pragma unroll
      for (int ks = 1; ks < 4; ++ks) {
        acc0 = __builtin_amdgcn_mfma_f32_32x32x16_bf16(aW[ks], bB[ks][0], acc0, 0, 0, 0);
        acc1 = __builtin_amdgcn_mfma_f32_32x32x16_bf16(aW[ks], bB[ks][1], acc1, 0, 0, 0);
      }
      __builtin_amdgcn_s_setprio(0);

      #pragma unroll
      for (int rt = 0; rt < 2; ++rt) {
        const f32x16& A = rt ? acc1 : acc0;
        unsigned d[8];
        #pragma unroll
        for (int p = 0; p < 8; ++p) {
          float v0 = A[2 * p];     v0 = v0 > 0.f ? v0 : 0.f;
          float v1 = A[2 * p + 1]; v1 = v1 > 0.f ? v1 : 0.f;
          __asm__("v_cvt_pk_bf16_f32 %0, %1, %2" : "=v"(d[p]) : "v"(v0), "v"(v1));
        }
        __asm__("v_permlane32_swap_b32 %0, %1" : "+v"(d[0]), "+v"(d[2]));
        __asm__("v_permlane32_swap_b32 %0, %1" : "+v"(d[1]), "+v"(d[3]));
        __asm__("v_permlane32_swap_b32 %0, %1" : "+v"(d[4]), "+v"(d[6]));
        __asm__("v_permlane32_swap_b32 %0, %1" : "+v"(d[5]), "+v"(d[7]));
        union { unsigned u[4]; bf16x8 v; } f0, f1;
        f0.u[0] = d[0]; f0.u[1] = d[1]; f0.u[2] = d[2]; f0.u[3] = d[3];
        f1.u[0] = d[4]; f1.u[1] = d[5]; f1.u[2] = d[6]; f1.u[3] = d[7];
        aF[rt][2 * mt]     = f0.v;
        aF[rt][2 * mt + 1] = f1.v;
      }
    }

    if (ji == 0) __syncthreads();   // W2 DMA landed (vmcnt drain + all waves)

    // ---- phase 2+3: rolling 4-deep B-frag pipeline; b2 folded into C-in ----
    float dacc0[16], dacc1[16];
    #pragma unroll
    for (int r = 0; r < 16; ++r) { dacc0[r] = 0.f; dacc1[r] = 0.f; }

    bf16x8 f[4];   // circular buffer, statically indexed (full unroll)
    #pragma unroll
    for (int p = 0; p < 4; ++p)
      f[p] = *reinterpret_cast<const bf16x8*>(sW2 + (size_t)(p * 64 + lane) * 8);

    #pragma unroll
    for (int ct = 0; ct < 8; ++ct) {
      f32x16 b2i;
      #pragma unroll
      for (int r = 0; r < 16; ++r) b2i[r] = b2v[ct];

      f32x16 acc0, acc1;
      #pragma unroll
      for (int s2 = 0; s2 < 16; ++s2) {
        const bf16x8 cur = f[s2 & 3];              // frag ct*16+s2
        const int nidx = ct * 16 + s2 + 4;         // prefetch 4 ahead
        if (nidx < 128)
          f[s2 & 3] = *reinterpret_cast<const bf16x8*>(
              sW2 + (size_t)(nidx * 64 + lane) * 8);
        __builtin_amdgcn_s_setprio(1);
        if (s2 == 0) {
          acc0 = __builtin_amdgcn_mfma_f32_32x32x16_bf16(aF[0][0], cur, b2i, 0, 0, 0);
          acc1 = __builtin_amdgcn_mfma_f32_32x32x16_bf16(aF[1][0], cur, b2i, 0, 0, 0);
        } else {
          acc0 = __builtin_amdgcn_mfma_f32_32x32x16_bf16(aF[0][s2], cur, acc0, 0, 0, 0);
          acc1 = __builtin_amdgcn_mfma_f32_32x32x16_bf16(aF[1][s2], cur, acc1, 0, 0, 0);
        }
        __builtin_amdgcn_s_setprio(0);
      }

      // fused epilogue: relu(h2) dot W3 (bias already in C-in)
      #pragma unroll
      for (int r = 0; r < 16; ++r) {
        float v0 = acc0[r]; v0 = v0 > 0.f ? v0 : 0.f; dacc0[r] += v0 * w3v[ct];
        float v1 = acc1[r]; v1 = v1 > 0.f ? v1 : 0.f; dacc1[r] += v1 * w3v[ct];
      }
    }

    // ---- reduce over 32 n-lanes, write out ----
    #pragma unroll
    for (int r = 0; r < 16; ++r) {
      float v0 = dacc0[r], v1 = dacc1[r];
      v0 += __shfl_xor(v0, 1);  v1 += __shfl_xor(v1, 1);
      v0 += __shfl_xor(v0, 2);  v1 += __shfl_xor(v1, 2);
      v0 += __shfl_xor(v0, 4);  v1 += __shfl_xor(v1, 4);
      v0 += __shfl_xor(v0, 8);  v1 += __shfl_xor(v1, 8);
      v0 += __shfl_xor(v0, 16); v1 += __shfl_xor(v1, 16);
      dacc0[r] = v0; dacc1[r] = v1;
    }

    if (l31 == 0) {   // lanes 0 and 32 write (h5 splits the row groups)
      #pragma unroll
      for (int r = 0; r < 16; ++r) {
        const int rr = (r & 3) + 8 * (r >> 2) + 4 * h5;   // D row in 32-tile
        out[(size_t)(wrow + rr) * C + c]      = dacc0[r] + bb3;
        out[(size_t)(wrow + 32 + rr) * C + c] = dacc1[r] + bb3;
      }
    }
  }
}

extern "C" void kernel_launch(void* const* d_in, const int* in_sizes, int n_in,
                              void* d_out, int out_size, void* d_ws, size_t ws_size,
                              hipStream_t stream)
{
  const float* st = (const float*)d_in[0];
  const float* W1 = (const float*)d_in[1];
  const float* b1 = (const float*)d_in[2];
  const float* W2 = (const float*)d_in[3];
  const float* b2 = (const float*)d_in[4];
  const float* W3 = (const float*)d_in[5];
  const float* b3 = (const float*)d_in[6];
  float* out = (float*)d_out;

  unsigned short* W1F = (unsigned short*)d_ws;         // 131072 bf16
  unsigned short* W2F = W1F + C * HD * S;              // 524288 bf16

  prep_frags<<<dim3(320), dim3(256), 0, stream>>>(W1, W2, W1F, W2F);
  moe_fused<<<dim3(256), dim3(512), 0, stream>>>(st, W1F, W2F, b1, b2, W3, b3, out);
}

// Round 6
// 163.729 us; speedup vs baseline: 4.1057x; 1.2634x over previous
//
#include <hip/hip_runtime.h>
#include <hip/hip_bf16.h>

typedef __bf16 bf16x8 __attribute__((ext_vector_type(8)));
typedef float  f32x4  __attribute__((ext_vector_type(4)));

static constexpr int S  = 64;    // DIM_S
static constexpr int C  = 8;     // DIM_C (experts)
static constexpr int HD = 256;   // hidden width

__device__ __forceinline__ unsigned short f2bf(float f) {
  __hip_bfloat16 b = __float2bfloat16(f);
  unsigned short u;
  __builtin_memcpy(&u, &b, 2);
  return u;
}

// async global->LDS DMA, 16 B per lane; lds dest = wave-uniform base + lane*16
__device__ __forceinline__ void gl2lds16(const void* g, void* l) {
  __builtin_amdgcn_global_load_lds(
      (const __attribute__((address_space(1))) unsigned int*)g,
      (__attribute__((address_space(3))) unsigned int*)l, 16, 0, 0);
}

// LDS-tiled transposes, coalesced both sides.
// blocks 0..511:  W2 [C][256k][256n] -> W2T bf16 [C][256n][256k]
// blocks 512..639: W1 [C][64s][256h] -> W1T bf16 [C][256h][64s]
__global__ __launch_bounds__(256) void prep_weights(
    const float* __restrict__ W1, const float* __restrict__ W2,
    unsigned short* __restrict__ W1T, unsigned short* __restrict__ W2T)
{
  __shared__ float tile[32][33];
  const int tid = threadIdx.x, cl = tid & 31, r0 = tid >> 5;
  const int b = blockIdx.x;
  if (b < 512) {
    const int c = b >> 6, t = b & 63, kt = t >> 3, nt = t & 7;
    const float* src = W2 + c * 65536;
    #pragma unroll
    for (int i = 0; i < 4; ++i) {
      int r = r0 + 8 * i;
      tile[r][cl] = src[(kt * 32 + r) * 256 + nt * 32 + cl];
    }
    __syncthreads();
    unsigned short* dst = W2T + c * 65536;
    #pragma unroll
    for (int i = 0; i < 4; ++i) {
      int r = r0 + 8 * i;
      dst[(nt * 32 + r) * 256 + kt * 32 + cl] = f2bf(tile[cl][r]);
    }
  } else {
    const int bb = b - 512;
    const int c = bb >> 4, t = bb & 15, st2 = t >> 3, ht = t & 7;
    const float* src = W1 + c * 16384;
    #pragma unroll
    for (int i = 0; i < 4; ++i) {
      int r = r0 + 8 * i;
      tile[r][cl] = src[(st2 * 32 + r) * 256 + ht * 32 + cl];
    }
    __syncthreads();
    unsigned short* dst = W1T + c * 16384;
    #pragma unroll
    for (int i = 0; i < 4; ++i) {
      int r = r0 + 8 * i;
      dst[(ht * 32 + r) * 64 + st2 * 32 + cl] = f2bf(tile[cl][r]);
    }
  }
}

// One block: 256 batch rows x 1 expert. 4 waves, 64 rows/wave.
// Structure identical to the 113us round-0 kernel (best measured). This round
// applies ONLY a VALU diet: cvt_pk packing, b1/b2 folded into MFMA C-in,
// setprio around MFMA clusters. No register-structure changes (R3-R5 lesson:
// aF-persistent redesigns hit the 256-reg cliff and serialize on latency).
__global__ __launch_bounds__(256, 2) void moe_fused(
    const float* __restrict__ st,
    const unsigned short* __restrict__ W1T,
    const unsigned short* __restrict__ W2T,
    const float* __restrict__ b1,
    const float* __restrict__ b2,
    const float* __restrict__ W3,
    const float* __restrict__ b3,
    float* __restrict__ out)
{
  constexpr int LDT = 72;   // sT pitch: 64 + 8 pad bf16 (144 B rows, 16B-aligned)

  __shared__ __align__(16) unsigned short sT[256 * LDT];   // 36864 B transpose buf
  // sU: phase 1 = st tile bf16 [256 rows][64], granule-swizzled (g^(r&7));
  //     phase 2 = W2 ping-pong 2 x (32 rows x 256 bf16), same swizzle. 32768 B.
  __shared__ __align__(16) unsigned short sU[2 * 32 * 256];

  const int tid  = threadIdx.x;
  const int lane = tid & 63;
  const int wv   = tid >> 6;          // wave -> batch rows [wv*64, wv*64+64)
  const int l15  = lane & 15;
  const int q    = lane >> 4;
  const int c    = blockIdx.x >> 8;
  const int row0 = (blockIdx.x & 255) * 256;

  const unsigned short* W1c = W1T + c * HD * S;
  const unsigned short* W2c = W2T + c * HD * HD;

  // ---- stage st (fp32 -> bf16 via cvt_pk) into sU; wave-private rows ----
  {
    #pragma unroll
    for (int it = 0; it < 8; ++it) {
      const int r = wv * 64 + it * 8 + (lane >> 3);   // block-local batch row
      const int g = lane & 7;                          // logical granule (8 bf16)
      const float4* p = reinterpret_cast<const float4*>(
          st + (size_t)(row0 + r) * S + g * 8);
      float4 x = p[0], y = p[1];
      union { uint4 u4; unsigned u[4]; } pk;
      __asm__("v_cvt_pk_bf16_f32 %0, %1, %2" : "=v"(pk.u[0]) : "v"(x.x), "v"(x.y));
      __asm__("v_cvt_pk_bf16_f32 %0, %1, %2" : "=v"(pk.u[1]) : "v"(x.z), "v"(x.w));
      __asm__("v_cvt_pk_bf16_f32 %0, %1, %2" : "=v"(pk.u[2]) : "v"(y.x), "v"(y.y));
      __asm__("v_cvt_pk_bf16_f32 %0, %1, %2" : "=v"(pk.u[3]) : "v"(y.z), "v"(y.w));
      *reinterpret_cast<uint4*>(sU + r * 64 + ((g ^ (r & 7)) << 3)) = pk.u4;
    }
  }
  __asm__ __volatile__("s_waitcnt lgkmcnt(0)" ::: "memory");

  // ---- phase 1: h1^T[hidden][batch] = W1^T @ st^T, 4 quarters of 64 hidden ----
  bf16x8 aF[4][4][2];  // [cc][rt][k2]: phase-2 A-frags (m=batch l15, k=hidden)
  #pragma unroll
  for (int cc = 0; cc < 4; ++cc) {
    f32x4 bias[4];
    #pragma unroll
    for (int mt = 0; mt < 4; ++mt)
      bias[mt] = *reinterpret_cast<const f32x4*>(
          b1 + c * HD + cc * 64 + mt * 16 + q * 4);

    // b1 folded into MFMA C-in: D row = hidden = q*4+j, exactly bias[mt]'s
    // layout (same indexing the verified epilogue used for its adds).
    f32x4 acc[4][4];   // [mt(hidden)][nt(batch)]
    #pragma unroll
    for (int mt = 0; mt < 4; ++mt)
      #pragma unroll
      for (int nt = 0; nt < 4; ++nt)
        acc[mt][nt] = bias[mt];

    #pragma unroll
    for (int ks = 0; ks < 2; ++ks) {
      // A-frags: W1T rows (hidden as M), global, L1/L2-hot under c-major grid
      bf16x8 aW[4];
      #pragma unroll
      for (int mt = 0; mt < 4; ++mt)
        aW[mt] = *reinterpret_cast<const bf16x8*>(
            W1c + (cc * 64 + mt * 16 + l15) * S + ks * 32 + q * 8);
      // B-frags: st rows (batch as N) from swizzled sU
      bf16x8 bB[4];
      #pragma unroll
      for (int nt = 0; nt < 4; ++nt) {
        const int r = wv * 64 + nt * 16 + l15;
        const int g = ks * 4 + q;
        bB[nt] = *reinterpret_cast<const bf16x8*>(
            sU + r * 64 + ((g ^ (r & 7)) << 3));
      }
      __builtin_amdgcn_s_setprio(1);
      #pragma unroll
      for (int mt = 0; mt < 4; ++mt)
        #pragma unroll
        for (int nt = 0; nt < 4; ++nt)
          acc[mt][nt] = __builtin_amdgcn_mfma_f32_16x16x32_bf16(
              aW[mt], bB[nt], acc[mt][nt], 0, 0, 0);
      __builtin_amdgcn_s_setprio(0);
    }

    // epilogue: relu (bias already in C-in), cvt_pk -> one b64 write.
    // sT rows [wv*64, wv*64+64) are wave-private: lgkmcnt drain, no barrier.
    #pragma unroll
    for (int mt = 0; mt < 4; ++mt) {
      #pragma unroll
      for (int nt = 0; nt < 4; ++nt) {
        float v0 = acc[mt][nt][0]; v0 = v0 > 0.f ? v0 : 0.f;
        float v1 = acc[mt][nt][1]; v1 = v1 > 0.f ? v1 : 0.f;
        float v2 = acc[mt][nt][2]; v2 = v2 > 0.f ? v2 : 0.f;
        float v3 = acc[mt][nt][3]; v3 = v3 > 0.f ? v3 : 0.f;
        uint2 pk;
        __asm__("v_cvt_pk_bf16_f32 %0, %1, %2" : "=v"(pk.x) : "v"(v0), "v"(v1));
        __asm__("v_cvt_pk_bf16_f32 %0, %1, %2" : "=v"(pk.y) : "v"(v2), "v"(v3));
        *reinterpret_cast<uint2*>(
            sT + (wv * 64 + nt * 16 + l15) * LDT + mt * 16 + q * 4) = pk;
      }
    }
    __asm__ __volatile__("s_waitcnt lgkmcnt(0)" ::: "memory");
    #pragma unroll
    for (int rt = 0; rt < 4; ++rt)
      #pragma unroll
      for (int k2 = 0; k2 < 2; ++k2)
        aF[cc][rt][k2] = *reinterpret_cast<const bf16x8*>(
            sT + (wv * 64 + rt * 16 + l15) * LDT + k2 * 32 + q * 8);
    __asm__ __volatile__("s_waitcnt lgkmcnt(0)" ::: "memory");  // WAR guard
  }

  // ---- phase-2/3 scalars: loaded BEFORE any DMA is issued (vmcnt FIFO) ----
  float pb2v[8][2], pw3v[8][2];
  #pragma unroll
  for (int ch = 0; ch < 8; ++ch)
    #pragma unroll
    for (int ct = 0; ct < 2; ++ct) {
      const int n = ch * 32 + ct * 16 + l15;
      pb2v[ch][ct] = b2[c * HD + n];
      pw3v[ch][ct] = W3[c * HD + n];
    }
  const float bb3 = b3[c];

  __syncthreads();   // barrier #1: ALL waves done reading sU-as-st (union safety)

  // ---- DMA prologue: W2 chunks 0,1 into sU (now free) ----
  #pragma unroll
  for (int pc = 0; pc < 2; ++pc) {
    unsigned short* buf = sU + pc * (32 * 256);
    #pragma unroll
    for (int i = 0; i < 4; ++i) {
      const int b2i = wv * 4 + i;            // 1KB unit (2 rows)
      const int r   = b2i * 2 + (lane >> 5); // local row 0..31
      const int j   = (lane & 31) ^ (r & 7); // logical granule
      gl2lds16(W2c + (pc * 32 + r) * 256 + j * 8, buf + b2i * 512);
    }
  }
  __syncthreads();   // barrier #2: drains vmcnt(0) -> chunks 0,1 landed

  // ---- phase 2+3: d = relu(h1 @ W2 + b2) . W3, chunk ping-pong ----
  float dacc[4][4];
  #pragma unroll
  for (int rt = 0; rt < 4; ++rt)
    #pragma unroll
    for (int r = 0; r < 4; ++r) dacc[rt][r] = 0.f;

  #pragma unroll
  for (int ch = 0; ch < 8; ++ch) {
    const unsigned short* buf = sU + (ch & 1) * (32 * 256);

    // b2 folded into MFMA C-in: D col = n-col = l15 -> splat pb2v across rows
    f32x4 acc[4][2];
    #pragma unroll
    for (int rt = 0; rt < 4; ++rt)
      #pragma unroll
      for (int ct = 0; ct < 2; ++ct) {
        const float bv = pb2v[ch][ct];
        acc[rt][ct] = (f32x4){bv, bv, bv, bv};
      }

    #pragma unroll
    for (int ks = 0; ks < 8; ++ks) {
      const int jj = ks * 4 + q;            // logical granule of this k-slice
      const int cc = ks >> 1, k2 = ks & 1;
      #pragma unroll
      for (int ct = 0; ct < 2; ++ct) {
        const int nl = ct * 16 + l15;       // local row (= h2 col within chunk)
        bf16x8 b = *reinterpret_cast<const bf16x8*>(
            buf + nl * 256 + ((jj ^ (l15 & 7)) << 3));
        __builtin_amdgcn_s_setprio(1);
        #pragma unroll
        for (int rt = 0; rt < 4; ++rt)
          acc[rt][ct] = __builtin_amdgcn_mfma_f32_16x16x32_bf16(
              aF[cc][rt][k2], b, acc[rt][ct], 0, 0, 0);
        __builtin_amdgcn_s_setprio(0);
      }
    }

    // fused epilogue: relu(h2) dot W3 per row (bias already in C-in)
    #pragma unroll
    for (int ct = 0; ct < 2; ++ct) {
      const float w3v = pw3v[ch][ct];
      #pragma unroll
      for (int rt = 0; rt < 4; ++rt)
        #pragma unroll
        for (int r = 0; r < 4; ++r) {
          float v = acc[rt][ct][r];
          v = v > 0.f ? v : 0.f;
          dacc[rt][r] += v * w3v;
        }
    }

    __syncthreads();   // readers of buf[ch&1] done; drains chunk ch+1's DMA
    if (ch < 6) {      // refill freed buffer with chunk ch+2 (1 chunk in flight)
      unsigned short* nbuf = sU + (ch & 1) * (32 * 256);
      #pragma unroll
      for (int i = 0; i < 4; ++i) {
        const int b2i = wv * 4 + i;
        const int r   = b2i * 2 + (lane >> 5);
        const int j   = (lane & 31) ^ (r & 7);
        gl2lds16(W2c + ((ch + 2) * 32 + r) * 256 + j * 8, nbuf + b2i * 512);
      }
    }
  }

  // ---- reduce over the 16 col-lanes, write out ----
  #pragma unroll
  for (int rt = 0; rt < 4; ++rt)
    #pragma unroll
    for (int r = 0; r < 4; ++r) {
      float v = dacc[rt][r];
      v += __shfl_xor(v, 1);
      v += __shfl_xor(v, 2);
      v += __shfl_xor(v, 4);
      v += __shfl_xor(v, 8);
      dacc[rt][r] = v;
    }

  if (l15 == 0) {
    const int rbase = row0 + wv * 64 + q * 4;
    #pragma unroll
    for (int rt = 0; rt < 4; ++rt)
      #pragma unroll
      for (int r = 0; r < 4; ++r)
        out[(rbase + rt * 16 + r) * C + c] = dacc[rt][r] + bb3;
  }
}

extern "C" void kernel_launch(void* const* d_in, const int* in_sizes, int n_in,
                              void* d_out, int out_size, void* d_ws, size_t ws_size,
                              hipStream_t stream)
{
  const float* st = (const float*)d_in[0];
  const float* W1 = (const float*)d_in[1];
  const float* b1 = (const float*)d_in[2];
  const float* W2 = (const float*)d_in[3];
  const float* b2 = (const float*)d_in[4];
  const float* W3 = (const float*)d_in[5];
  const float* b3 = (const float*)d_in[6];
  float* out = (float*)d_out;

  unsigned short* W1T = (unsigned short*)d_ws;         // 131072 bf16
  unsigned short* W2T = W1T + C * HD * S;              // 524288 bf16

  prep_weights<<<dim3(640), dim3(256), 0, stream>>>(W1, W2, W1T, W2T);
  moe_fused<<<dim3(2048), dim3(256), 0, stream>>>(st, W1T, W2T, b1, b2, W3, b3, out);
}